// Round 15
// baseline (142.633 us; speedup 1.0000x reference)
//
#include <hip/hip_runtime.h>
#include <hip/hip_bf16.h>

#define N_NODES 50000
#define BSHIFT  6
#define BSIZE   64
#define NBUCK   ((N_NODES + BSIZE - 1) / BSIZE)   // 782
#define BIN_BLOCKS 512

using short8  = __attribute__((ext_vector_type(8))) short;
using short4v = __attribute__((ext_vector_type(4))) short;
using floatx4 = __attribute__((ext_vector_type(4))) float;

__device__ inline short f32_to_bf16_bits(float f) {
    __hip_bfloat16 h = __float2bfloat16(f);
    return *reinterpret_cast<short*>(&h);
}

// ---------------- MFMA GEMM (layer 1 only): coalesced loads ----------------
template<int K, int N, bool A_F32>
__global__ __launch_bounds__(256) void mfma_gemm(const void* __restrict__ Araw,
                                                 const short* __restrict__ WTf,
                                                 const float* __restrict__ bias,
                                                 short* __restrict__ C, int M)
{
    constexpr int KS = K / 32;
    constexpr int CT = N / 32;
    constexpr int LK = K + 8;

    __shared__ __align__(16) short As[64][LK];

    const int tid  = threadIdx.x;
    const int wave = tid >> 6;
    const int lane = tid & 63;
    const int l15  = lane & 15;
    const int lk   = (lane >> 4) * 8;
    const int wr   = wave >> 1;
    const int wc   = wave & 1;
    const int r0   = blockIdx.x * 64;

    if (A_F32) {
        const float* Af = (const float*)Araw;
#pragma unroll
        for (int it = 0; it < 64 * (K / 4) / 256; ++it) {
            const int idx = it * 256 + tid;
            const int row = idx / (K / 4);
            const int c4  = idx % (K / 4);
            const int gr  = min(r0 + row, M - 1);
            const float4 v = *reinterpret_cast<const float4*>(&Af[(size_t)gr * K + c4 * 4]);
            short4v s;
            s[0] = f32_to_bf16_bits(v.x); s[1] = f32_to_bf16_bits(v.y);
            s[2] = f32_to_bf16_bits(v.z); s[3] = f32_to_bf16_bits(v.w);
            *reinterpret_cast<short4v*>(&As[row][c4 * 4]) = s;
        }
    } else {
        const short* Ab = (const short*)Araw;
#pragma unroll
        for (int it = 0; it < 64 * (K / 8) / 256; ++it) {
            const int idx = it * 256 + tid;
            const int row = idx / (K / 8);
            const int c8  = idx % (K / 8);
            const int gr  = min(r0 + row, M - 1);
            const short8 v = *reinterpret_cast<const short8*>(&Ab[(size_t)gr * K + c8 * 8]);
            *reinterpret_cast<short8*>(&As[row][c8 * 8]) = v;
        }
    }
    __syncthreads();

    float bv[CT];
#pragma unroll
    for (int t = 0; t < CT; ++t) bv[t] = bias[wc * (N / 2) + t * 16 + l15];

    floatx4 acc[2][CT];
#pragma unroll
    for (int rt = 0; rt < 2; ++rt)
#pragma unroll
        for (int t = 0; t < CT; ++t) acc[rt][t] = (floatx4){0.f, 0.f, 0.f, 0.f};

#pragma unroll
    for (int ks = 0; ks < KS; ++ks) {
        short8 b[CT];
#pragma unroll
        for (int t = 0; t < CT; ++t) {
            const int tg = wc * CT + t;
            b[t] = *reinterpret_cast<const short8*>(&WTf[((size_t)(tg * KS + ks) * 64 + lane) * 8]);
        }
        short8 a[2];
#pragma unroll
        for (int rt = 0; rt < 2; ++rt)
            a[rt] = *reinterpret_cast<const short8*>(&As[wr * 32 + rt * 16 + l15][ks * 32 + lk]);
#pragma unroll
        for (int rt = 0; rt < 2; ++rt)
#pragma unroll
            for (int t = 0; t < CT; ++t)
                acc[rt][t] = __builtin_amdgcn_mfma_f32_16x16x32_bf16(a[rt], b[t], acc[rt][t], 0, 0, 0);
    }

    const int rowg = (lane >> 4) * 4;
#pragma unroll
    for (int rt = 0; rt < 2; ++rt)
#pragma unroll
        for (int t = 0; t < CT; ++t)
#pragma unroll
            for (int j = 0; j < 4; ++j) {
                const int gr = r0 + wr * 32 + rt * 16 + rowg + j;
                if (gr < M)
                    C[(size_t)gr * N + wc * (N / 2) + t * 16 + l15] =
                        f32_to_bf16_bits(acc[rt][t][j] + bv[t]);
            }
}

// ---------------- FUSED: pull (32 nodes, D=128) -> relu -> GEMM ----------------
// Block = 32 nodes, 4 waves (256 thr). Pull: 4 concurrent nodes/wave
// (16 lanes x uint4 per node), 2 rounds. GEMM: wave = 16 rows x N/2 cols.
template<int K, int N>
__global__ __launch_bounds__(256) void fused_pull_gemm(const unsigned int* __restrict__ h,
                                                       const int* __restrict__ row_ptr,
                                                       const unsigned int* __restrict__ csr_ew,
                                                       const short* __restrict__ WTf,
                                                       const float* __restrict__ bias,
                                                       short* __restrict__ C, int M)
{
    static_assert(K == 128, "pull input dim is 128");
    constexpr int KS   = K / 32;
    constexpr int LK   = K + 8;
    constexpr int COLT = N / 32;            // col-tiles per wave (4 or 2)

    __shared__ __align__(16) short As[32][LK];

    const int tid  = threadIdx.x;
    const int wave = tid >> 6;
    const int lane = tid & 63;
    const int q    = lane >> 4;
    const int l16  = lane & 15;
    const int r0   = blockIdx.x * 32;

    // ---- Pull: 2 rounds x 4 concurrent nodes per wave ----
#pragma unroll
    for (int rnd = 0; rnd < 2; ++rnd) {
        const int lrow = wave * 8 + rnd * 4 + q;
        const int node = r0 + lrow;
        int beg = 0, end = 0;
        if (node < M) { beg = row_ptr[node]; end = row_ptr[node + 1]; }

        float ax[4][4], ay[4][4];
#pragma unroll
        for (int u = 0; u < 4; ++u)
#pragma unroll
            for (int jj = 0; jj < 4; ++jj) { ax[u][jj] = 0.f; ay[u][jj] = 0.f; }

        for (int c = beg; c < end; c += 16) {
            const int idx = c + l16;
            const unsigned ew = (idx < end) ? csr_ew[idx] : 0u;
            const int cnt = min(16, end - c);
            for (int j = 0; j < cnt; j += 4) {
                unsigned e[4];
#pragma unroll
                for (int u = 0; u < 4; ++u) {
                    const unsigned v = __shfl(ew, j + u, 16);
                    e[u] = (j + u < cnt) ? v : 0u;       // pad: src=0, w=+0.0
                }
                uint4 p[4];
#pragma unroll
                for (int u = 0; u < 4; ++u)
                    p[u] = *reinterpret_cast<const uint4*>(&h[(size_t)(e[u] >> 16) * 64 + l16 * 4]);
#pragma unroll
                for (int u = 0; u < 4; ++u) {
                    const float wv = __int_as_float(e[u] << 16);
                    const unsigned* pp = reinterpret_cast<const unsigned*>(&p[u]);
#pragma unroll
                    for (int jj = 0; jj < 4; ++jj) {
                        ax[u][jj] = fmaf(__int_as_float(pp[jj] << 16), wv, ax[u][jj]);
                        ay[u][jj] = fmaf(__int_as_float(pp[jj] & 0xffff0000u), wv, ay[u][jj]);
                    }
                }
            }
        }

        // zero-writes for node >= M keep the LDS tile defined
        uint4 o;
        unsigned* ov = reinterpret_cast<unsigned*>(&o);
#pragma unroll
        for (int jj = 0; jj < 4; ++jj) {
            float axs = (ax[0][jj] + ax[1][jj]) + (ax[2][jj] + ax[3][jj]);
            float ays = (ay[0][jj] + ay[1][jj]) + (ay[2][jj] + ay[3][jj]);
            axs = fmaxf(axs, 0.f); ays = fmaxf(ays, 0.f);      // relu
            ov[jj] = (unsigned)(unsigned short)f32_to_bf16_bits(axs) |
                     ((unsigned)(unsigned short)f32_to_bf16_bits(ays) << 16);
        }
        *reinterpret_cast<uint4*>(&As[lrow][l16 * 8]) = o;
    }
    __syncthreads();

    // ---- GEMM from LDS (4 waves = 2 row-groups x 2 col-groups) ----
    const int l15 = lane & 15;
    const int lk  = (lane >> 4) * 8;
    const int wr  = wave >> 1;
    const int wc  = wave & 1;

    float bv[COLT];
#pragma unroll
    for (int t = 0; t < COLT; ++t) bv[t] = bias[wc * (N / 2) + t * 16 + l15];

    floatx4 acc[COLT];
#pragma unroll
    for (int t = 0; t < COLT; ++t) acc[t] = (floatx4){0.f, 0.f, 0.f, 0.f};

#pragma unroll
    for (int ks = 0; ks < KS; ++ks) {
        short8 b[COLT];
#pragma unroll
        for (int t = 0; t < COLT; ++t) {
            const int tg = wc * COLT + t;
            b[t] = *reinterpret_cast<const short8*>(&WTf[((size_t)(tg * KS + ks) * 64 + lane) * 8]);
        }
        const short8 a = *reinterpret_cast<const short8*>(&As[wr * 16 + l15][ks * 32 + lk]);
#pragma unroll
        for (int t = 0; t < COLT; ++t)
            acc[t] = __builtin_amdgcn_mfma_f32_16x16x32_bf16(a, b[t], acc[t], 0, 0, 0);
    }

    const int rowg = (lane >> 4) * 4;
#pragma unroll
    for (int t = 0; t < COLT; ++t)
#pragma unroll
        for (int j = 0; j < 4; ++j) {
            const int gr = r0 + wr * 16 + rowg + j;
            if (gr < M)
                C[(size_t)gr * N + wc * (N / 2) + t * 16 + l15] =
                    f32_to_bf16_bits(acc[t][j] + bv[t]);
        }
}

// ---------------- W -> fragment-ordered bf16 WTf ----------------
__device__ inline void wt_frag(const float* __restrict__ W, short* __restrict__ out,
                               int K, int N, int u)
{
    const int lane = u & 63;
    const int rest = u >> 6;
    const int KS   = K >> 5;
    const int ks   = rest % KS;
    const int tg   = rest / KS;
    const int n    = tg * 16 + (lane & 15);
    const int kb   = ks * 32 + (lane >> 4) * 8;
    short8 s;
#pragma unroll
    for (int e = 0; e < 8; ++e) s[e] = f32_to_bf16_bits(W[(size_t)(kb + e) * N + n]);
    *reinterpret_cast<short8*>(&out[(size_t)u * 8]) = s;
}

// ================= prep: bin_hist (blocks 0..BIN_BLOCKS-1) + wt transposes =================
__global__ __launch_bounds__(256) void prep_kernel(const int* __restrict__ dst,
                                                   int* __restrict__ hist_g, int E,
                                                   const float* __restrict__ W1, short* __restrict__ WT1,
                                                   const float* __restrict__ W2, short* __restrict__ WT2,
                                                   const float* __restrict__ W3, short* __restrict__ WT3)
{
    if (blockIdx.x < BIN_BLOCKS) {
        __shared__ int hist[NBUCK];
        for (int t = threadIdx.x; t < NBUCK; t += 256) hist[t] = 0;
        __syncthreads();
        const int chunk = (E + BIN_BLOCKS - 1) / BIN_BLOCKS;
        const int beg = blockIdx.x * chunk;
        const int end = min(beg + chunk, E);
        for (int i = beg + threadIdx.x; i < end; i += 256)
            atomicAdd(&hist[dst[i] >> BSHIFT], 1);
        __syncthreads();
        for (int t = threadIdx.x; t < NBUCK; t += 256)
            hist_g[blockIdx.x * NBUCK + t] = hist[t];
    } else {
        const int u = (blockIdx.x - BIN_BLOCKS) * 256 + threadIdx.x;
        if (u < 4096)             wt_frag(W1, WT1, 256, 128, u);
        else if (u < 4096 + 2048) wt_frag(W2, WT2, 128, 128, u - 4096);
        else if (u < 7168)        wt_frag(W3, WT3, 128, 64,  u - 6144);
    }
}

__global__ __launch_bounds__(BIN_BLOCKS) void bin_scan_blocks(const int* __restrict__ hist_g,
                                                              int* __restrict__ blockbase,
                                                              int* __restrict__ tot)
{
    __shared__ int s[BIN_BLOCKS];
    const int b = blockIdx.x;
    const int t = threadIdx.x;
    const int v = hist_g[t * NBUCK + b];
    s[t] = v;
    __syncthreads();
#pragma unroll
    for (int off = 1; off < BIN_BLOCKS; off <<= 1) {
        const int tmp = (t >= off) ? s[t - off] : 0;
        __syncthreads();
        s[t] += tmp;
        __syncthreads();
    }
    blockbase[t * NBUCK + b] = s[t] - v;
    if (t == BIN_BLOCKS - 1) tot[b] = s[t];
}

__global__ __launch_bounds__(256) void bin_scan_tot(const int* __restrict__ tot,
                                                    int* __restrict__ bucket_base)
{
    __shared__ int psum[256];
    const int t = threadIdx.x;
    int vals[4];
    int s = 0;
#pragma unroll
    for (int j = 0; j < 4; ++j) {
        const int idx = t * 4 + j;
        vals[j] = (idx < NBUCK) ? tot[idx] : 0;
        s += vals[j];
    }
    psum[t] = s;
    __syncthreads();
#pragma unroll
    for (int off = 1; off < 256; off <<= 1) {
        const int tmp = (t >= off) ? psum[t - off] : 0;
        __syncthreads();
        psum[t] += tmp;
        __syncthreads();
    }
    int run = psum[t] - s;
#pragma unroll
    for (int j = 0; j < 4; ++j) {
        const int idx = t * 4 + j;
        if (idx < NBUCK) bucket_base[idx] = run;
        run += vals[j];
    }
    if (t == 255) bucket_base[NBUCK] = run;
}

__global__ __launch_bounds__(256) void bin_write(const int* __restrict__ src,
                                                 const int* __restrict__ dst,
                                                 const float* __restrict__ w,
                                                 const int* __restrict__ blockbase,
                                                 const int* __restrict__ bucket_base,
                                                 int2* __restrict__ tmp, int E)
{
    __shared__ int cur[NBUCK];
    for (int t = threadIdx.x; t < NBUCK; t += 256)
        cur[t] = bucket_base[t] + blockbase[blockIdx.x * NBUCK + t];
    __syncthreads();
    const int chunk = (E + BIN_BLOCKS - 1) / BIN_BLOCKS;
    const int beg = blockIdx.x * chunk;
    const int end = min(beg + chunk, E);
    for (int i = beg + threadIdx.x; i < end; i += 256) {
        const int d = dst[i];
        const int pos = atomicAdd(&cur[d >> BSHIFT], 1);
        tmp[pos] = make_int2((src[i] << BSHIFT) | (d & (BSIZE - 1)), __float_as_int(w[i]));
    }
}

// Pass D: one block per bucket. row_ptr + node-sorted packed 4B csr: (src<<16)|bf16(w)
__global__ __launch_bounds__(256) void fine_fill2(const int2* __restrict__ tmp,
                                                  const int* __restrict__ bucket_base,
                                                  unsigned int* __restrict__ csr_ew,
                                                  int* __restrict__ row_ptr)
{
    __shared__ int hist[BSIZE];
    __shared__ int basel[BSIZE];
    const int b    = blockIdx.x;
    const int t    = threadIdx.x;
    const int rbeg = bucket_base[b];
    const int rend = bucket_base[b + 1];

    if (t < BSIZE) hist[t] = 0;
    __syncthreads();
    for (int i = rbeg + t; i < rend; i += 256)
        atomicAdd(&hist[((unsigned)tmp[i].x) & (BSIZE - 1)], 1);
    __syncthreads();

    if (t < BSIZE) {
        const int v = hist[t];
        int inc = v;
#pragma unroll
        for (int off = 1; off < BSIZE; off <<= 1) {
            const int u = __shfl_up(inc, off, 64);
            if (t >= off) inc += u;
        }
        const int excl = rbeg + inc - v;
        basel[t] = excl;
        const int node = (b << BSHIFT) + t;
        if (node < N_NODES) row_ptr[node] = excl;
        if (b == NBUCK - 1 && t == 0) row_ptr[N_NODES] = bucket_base[NBUCK];
    }
    __syncthreads();

    for (int i = rbeg + t; i < rend; i += 256) {
        const int2 e = tmp[i];
        const unsigned ex = (unsigned)e.x;
        const int pos = atomicAdd(&basel[ex & (BSIZE - 1)], 1);
        const unsigned wb = (unsigned short)f32_to_bf16_bits(__int_as_float(e.y));
        csr_ew[pos] = ((ex >> BSHIFT) << 16) | wb;
    }
}

// ---------------- pull (bf16 h, D=64): 4 nodes per wave (16 lanes x uint2), f32 out ----------------
__global__ __launch_bounds__(256) void pull64_bf(const unsigned int* __restrict__ h,
                                                 const int* __restrict__ row_ptr,
                                                 const unsigned int* __restrict__ csr_ew,
                                                 float4* __restrict__ out, int n_nodes)
{
    const int wave = threadIdx.x >> 6;
    const int lane = threadIdx.x & 63;
    const int q    = lane >> 4;
    const int l16  = lane & 15;
    const int node = blockIdx.x * 16 + wave * 4 + q;

    int beg = 0, end = 0;
    if (node < n_nodes) { beg = row_ptr[node]; end = row_ptr[node + 1]; }

    float ax[4][2], ay[4][2];
#pragma unroll
    for (int u = 0; u < 4; ++u)
#pragma unroll
        for (int jj = 0; jj < 2; ++jj) { ax[u][jj] = 0.f; ay[u][jj] = 0.f; }

    for (int c = beg; c < end; c += 16) {
        const int idx = c + l16;
        const unsigned ew = (idx < end) ? csr_ew[idx] : 0u;
        const int cnt = min(16, end - c);
        for (int j = 0; j < cnt; j += 4) {
            unsigned e[4];
#pragma unroll
            for (int u = 0; u < 4; ++u) {
                const unsigned v = __shfl(ew, j + u, 16);
                e[u] = (j + u < cnt) ? v : 0u;
            }
            uint2 p[4];
#pragma unroll
            for (int u = 0; u < 4; ++u)
                p[u] = *reinterpret_cast<const uint2*>(&h[(size_t)(e[u] >> 16) * 32 + l16 * 2]);
#pragma unroll
            for (int u = 0; u < 4; ++u) {
                const float wv = __int_as_float(e[u] << 16);
                ax[u][0] = fmaf(__int_as_float(p[u].x << 16), wv, ax[u][0]);
                ay[u][0] = fmaf(__int_as_float(p[u].x & 0xffff0000u), wv, ay[u][0]);
                ax[u][1] = fmaf(__int_as_float(p[u].y << 16), wv, ax[u][1]);
                ay[u][1] = fmaf(__int_as_float(p[u].y & 0xffff0000u), wv, ay[u][1]);
            }
        }
    }

    if (node < n_nodes) {
        float4 o;
        o.x = (ax[0][0] + ax[1][0]) + (ax[2][0] + ax[3][0]);
        o.y = (ay[0][0] + ay[1][0]) + (ay[2][0] + ay[3][0]);
        o.z = (ax[0][1] + ax[1][1]) + (ax[2][1] + ax[3][1]);
        o.w = (ay[0][1] + ay[1][1]) + (ay[2][1] + ay[3][1]);
        out[(size_t)node * 16 + l16] = o;
    }
}

extern "C" void kernel_launch(void* const* d_in, const int* in_sizes, int n_in,
                              void* d_out, int out_size, void* d_ws, size_t ws_size,
                              hipStream_t stream)
{
    const float* x   = (const float*)d_in[0];
    const int*   src = (const int*)  d_in[1];
    const int*   dst = (const int*)  d_in[2];
    const float* w   = (const float*)d_in[3];
    const float* W1  = (const float*)d_in[4];
    const float* b1  = (const float*)d_in[5];
    const float* W2  = (const float*)d_in[6];
    const float* b2  = (const float*)d_in[7];
    const float* W3  = (const float*)d_in[8];
    const float* b3  = (const float*)d_in[9];

    const int E = in_sizes[1];
    const int M = N_NODES;

    // workspace layout
    short* hA  = (short*)d_ws;                        // M*128 bf16 (h1 / h3)
    short* hB  = hA + (size_t)M * 128;                // M*128 bf16 (h2)
    short* WT1 = hB + (size_t)M * 128;                // frag-ordered
    short* WT2 = WT1 + 128 * 256;
    short* WT3 = WT2 + 128 * 128;
    unsigned int* csr_ew = (unsigned int*)(WT3 + 64 * 128);  // E u32
    int2*  tmp_ew      = (int2*)(csr_ew + ((E + 1) & ~1));   // E pairs
    int*   row_ptr     = (int*)(tmp_ew + E);          // 50048
    int*   hist_g      = row_ptr + 50048;             // 512*782 -> pad 401408
    int*   blockbase   = hist_g + 401408;             // 512*782 -> pad 401408
    int*   bucket_base = blockbase + 401408;          // 783 -> pad 1024
    int*   tot         = bucket_base + 1024;          // 782 -> pad 1024

    // ---- build (weights + CSR), no global atomics ----
    prep_kernel<<<BIN_BLOCKS + 28, 256, 0, stream>>>(dst, hist_g, E, W1, WT1, W2, WT2, W3, WT3);
    bin_scan_blocks<<<NBUCK, BIN_BLOCKS, 0, stream>>>(hist_g, blockbase, tot);
    bin_scan_tot<<<1, 256, 0, stream>>>(tot, bucket_base);
    bin_write<<<BIN_BLOCKS, 256, 0, stream>>>(src, dst, w, blockbase, bucket_base, tmp_ew, E);
    fine_fill2<<<NBUCK, 256, 0, stream>>>(tmp_ew, bucket_base, csr_ew, row_ptr);

    // ---- Layer 1 GEMM: x @ W1 -> h1 (hA) ----
    mfma_gemm<256, 128, true><<<(M + 63) / 64, 256, 0, stream>>>(x, WT1, b1, hA, M);

    const int fb = (M + 31) / 32;   // 1563 fused blocks
    // ---- Fused: pull(h1) -> relu -> @W2 -> h2 (hB) ----
    fused_pull_gemm<128, 128><<<fb, 256, 0, stream>>>((const unsigned int*)hA, row_ptr, csr_ew,
                                                      WT2, b2, hB, M);
    // ---- Fused: pull(h2) -> relu -> @W3 -> h3 (hA) ----
    fused_pull_gemm<128, 64><<<fb, 256, 0, stream>>>((const unsigned int*)hB, row_ptr, csr_ew,
                                                     WT3, b3, hA, M);
    // ---- Final pull: out = segsum(h3) ----
    pull64_bf<<<(M + 15) / 16, 256, 0, stream>>>((const unsigned int*)hA, row_ptr, csr_ew,
                                                 (float4*)d_out, M);
}

// Round 16
// 135.683 us; speedup vs baseline: 1.0512x; 1.0512x over previous
//
#include <hip/hip_runtime.h>
#include <hip/hip_bf16.h>

#define N_NODES 50000
#define BSHIFT  6
#define BSIZE   64
#define NBUCK   ((N_NODES + BSIZE - 1) / BSIZE)   // 782
#define BIN_BLOCKS 512

using short8  = __attribute__((ext_vector_type(8))) short;
using short4v = __attribute__((ext_vector_type(4))) short;
using floatx4 = __attribute__((ext_vector_type(4))) float;

__device__ inline short f32_to_bf16_bits(float f) {
    __hip_bfloat16 h = __float2bfloat16(f);
    return *reinterpret_cast<short*>(&h);
}

// ---------------- MFMA GEMM (layer 1 only): coalesced loads ----------------
template<int K, int N, bool A_F32>
__global__ __launch_bounds__(256) void mfma_gemm(const void* __restrict__ Araw,
                                                 const short* __restrict__ WTf,
                                                 const float* __restrict__ bias,
                                                 short* __restrict__ C, int M)
{
    constexpr int KS = K / 32;
    constexpr int CT = N / 32;
    constexpr int LK = K + 8;

    __shared__ __align__(16) short As[64][LK];

    const int tid  = threadIdx.x;
    const int wave = tid >> 6;
    const int lane = tid & 63;
    const int l15  = lane & 15;
    const int lk   = (lane >> 4) * 8;
    const int wr   = wave >> 1;
    const int wc   = wave & 1;
    const int r0   = blockIdx.x * 64;

    if (A_F32) {
        const float* Af = (const float*)Araw;
#pragma unroll
        for (int it = 0; it < 64 * (K / 4) / 256; ++it) {
            const int idx = it * 256 + tid;
            const int row = idx / (K / 4);
            const int c4  = idx % (K / 4);
            const int gr  = min(r0 + row, M - 1);
            const float4 v = *reinterpret_cast<const float4*>(&Af[(size_t)gr * K + c4 * 4]);
            short4v s;
            s[0] = f32_to_bf16_bits(v.x); s[1] = f32_to_bf16_bits(v.y);
            s[2] = f32_to_bf16_bits(v.z); s[3] = f32_to_bf16_bits(v.w);
            *reinterpret_cast<short4v*>(&As[row][c4 * 4]) = s;
        }
    } else {
        const short* Ab = (const short*)Araw;
#pragma unroll
        for (int it = 0; it < 64 * (K / 8) / 256; ++it) {
            const int idx = it * 256 + tid;
            const int row = idx / (K / 8);
            const int c8  = idx % (K / 8);
            const int gr  = min(r0 + row, M - 1);
            const short8 v = *reinterpret_cast<const short8*>(&Ab[(size_t)gr * K + c8 * 8]);
            *reinterpret_cast<short8*>(&As[row][c8 * 8]) = v;
        }
    }
    __syncthreads();

    float bv[CT];
#pragma unroll
    for (int t = 0; t < CT; ++t) bv[t] = bias[wc * (N / 2) + t * 16 + l15];

    floatx4 acc[2][CT];
#pragma unroll
    for (int rt = 0; rt < 2; ++rt)
#pragma unroll
        for (int t = 0; t < CT; ++t) acc[rt][t] = (floatx4){0.f, 0.f, 0.f, 0.f};

#pragma unroll
    for (int ks = 0; ks < KS; ++ks) {
        short8 b[CT];
#pragma unroll
        for (int t = 0; t < CT; ++t) {
            const int tg = wc * CT + t;
            b[t] = *reinterpret_cast<const short8*>(&WTf[((size_t)(tg * KS + ks) * 64 + lane) * 8]);
        }
        short8 a[2];
#pragma unroll
        for (int rt = 0; rt < 2; ++rt)
            a[rt] = *reinterpret_cast<const short8*>(&As[wr * 32 + rt * 16 + l15][ks * 32 + lk]);
#pragma unroll
        for (int rt = 0; rt < 2; ++rt)
#pragma unroll
            for (int t = 0; t < CT; ++t)
                acc[rt][t] = __builtin_amdgcn_mfma_f32_16x16x32_bf16(a[rt], b[t], acc[rt][t], 0, 0, 0);
    }

    const int rowg = (lane >> 4) * 4;
#pragma unroll
    for (int rt = 0; rt < 2; ++rt)
#pragma unroll
        for (int t = 0; t < CT; ++t)
#pragma unroll
            for (int j = 0; j < 4; ++j) {
                const int gr = r0 + wr * 32 + rt * 16 + rowg + j;
                if (gr < M)
                    C[(size_t)gr * N + wc * (N / 2) + t * 16 + l15] =
                        f32_to_bf16_bits(acc[rt][t][j] + bv[t]);
            }
}

// ---------------- FUSED: pull (32 nodes, D=128) -> relu -> GEMM ----------------
// Block = 32 nodes, 4 waves (256 thr). Pull: 4 concurrent nodes/wave
// (16 lanes x uint4 per node), 8-deep gather groups + edge-chunk prefetch.
template<int K, int N>
__global__ __launch_bounds__(256) void fused_pull_gemm(const unsigned int* __restrict__ h,
                                                       const int* __restrict__ row_ptr,
                                                       const unsigned int* __restrict__ csr_ew,
                                                       const short* __restrict__ WTf,
                                                       const float* __restrict__ bias,
                                                       short* __restrict__ C, int M)
{
    static_assert(K == 128, "pull input dim is 128");
    constexpr int KS   = K / 32;
    constexpr int LK   = K + 8;
    constexpr int COLT = N / 32;            // col-tiles per wave (4 or 2)

    __shared__ __align__(16) short As[32][LK];

    const int tid  = threadIdx.x;
    const int wave = tid >> 6;
    const int lane = tid & 63;
    const int q    = lane >> 4;
    const int l16  = lane & 15;
    const int r0   = blockIdx.x * 32;

    // ---- Pull: 2 rounds x 4 concurrent nodes per wave ----
#pragma unroll
    for (int rnd = 0; rnd < 2; ++rnd) {
        const int lrow = wave * 8 + rnd * 4 + q;
        const int node = r0 + lrow;
        int beg = 0, end = 0;
        if (node < M) { beg = row_ptr[node]; end = row_ptr[node + 1]; }

        float ax[4][4], ay[4][4];
#pragma unroll
        for (int u = 0; u < 4; ++u)
#pragma unroll
            for (int jj = 0; jj < 4; ++jj) { ax[u][jj] = 0.f; ay[u][jj] = 0.f; }

        unsigned ew = (beg + l16 < end) ? csr_ew[beg + l16] : 0u;
        for (int c = beg; c < end; c += 16) {
            // prefetch next chunk's edge records
            const int nidx = c + 16 + l16;
            const unsigned ew_next = (nidx < end) ? csr_ew[nidx] : 0u;
            const int cnt = min(16, end - c);

            for (int j = 0; j < cnt; j += 8) {
                unsigned e[8];
#pragma unroll
                for (int u = 0; u < 8; ++u) {
                    const unsigned v = __shfl(ew, j + u, 16);
                    e[u] = (j + u < cnt) ? v : 0u;       // pad: src=0, w=+0.0
                }
                uint4 p[8];
#pragma unroll
                for (int u = 0; u < 8; ++u)
                    p[u] = *reinterpret_cast<const uint4*>(&h[(size_t)(e[u] >> 16) * 64 + l16 * 4]);
#pragma unroll
                for (int u = 0; u < 8; ++u) {
                    const float wv = __int_as_float(e[u] << 16);
                    const unsigned* pp = reinterpret_cast<const unsigned*>(&p[u]);
#pragma unroll
                    for (int jj = 0; jj < 4; ++jj) {
                        ax[u & 3][jj] = fmaf(__int_as_float(pp[jj] << 16), wv, ax[u & 3][jj]);
                        ay[u & 3][jj] = fmaf(__int_as_float(pp[jj] & 0xffff0000u), wv, ay[u & 3][jj]);
                    }
                }
            }
            ew = ew_next;
        }

        // zero-writes for node >= M keep the LDS tile defined
        uint4 o;
        unsigned* ov = reinterpret_cast<unsigned*>(&o);
#pragma unroll
        for (int jj = 0; jj < 4; ++jj) {
            float axs = (ax[0][jj] + ax[1][jj]) + (ax[2][jj] + ax[3][jj]);
            float ays = (ay[0][jj] + ay[1][jj]) + (ay[2][jj] + ay[3][jj]);
            axs = fmaxf(axs, 0.f); ays = fmaxf(ays, 0.f);      // relu
            ov[jj] = (unsigned)(unsigned short)f32_to_bf16_bits(axs) |
                     ((unsigned)(unsigned short)f32_to_bf16_bits(ays) << 16);
        }
        *reinterpret_cast<uint4*>(&As[lrow][l16 * 8]) = o;
    }
    __syncthreads();

    // ---- GEMM from LDS (4 waves = 2 row-groups x 2 col-groups) ----
    const int l15 = lane & 15;
    const int lk  = (lane >> 4) * 8;
    const int wr  = wave >> 1;
    const int wc  = wave & 1;

    float bv[COLT];
#pragma unroll
    for (int t = 0; t < COLT; ++t) bv[t] = bias[wc * (N / 2) + t * 16 + l15];

    floatx4 acc[COLT];
#pragma unroll
    for (int t = 0; t < COLT; ++t) acc[t] = (floatx4){0.f, 0.f, 0.f, 0.f};

#pragma unroll
    for (int ks = 0; ks < KS; ++ks) {
        short8 b[COLT];
#pragma unroll
        for (int t = 0; t < COLT; ++t) {
            const int tg = wc * COLT + t;
            b[t] = *reinterpret_cast<const short8*>(&WTf[((size_t)(tg * KS + ks) * 64 + lane) * 8]);
        }
        const short8 a = *reinterpret_cast<const short8*>(&As[wr * 16 + l15][ks * 32 + lk]);
#pragma unroll
        for (int t = 0; t < COLT; ++t)
            acc[t] = __builtin_amdgcn_mfma_f32_16x16x32_bf16(a, b[t], acc[t], 0, 0, 0);
    }

    const int rowg = (lane >> 4) * 4;
#pragma unroll
    for (int t = 0; t < COLT; ++t)
#pragma unroll
        for (int j = 0; j < 4; ++j) {
            const int gr = r0 + wr * 16 + rowg + j;
            if (gr < M)
                C[(size_t)gr * N + wc * (N / 2) + t * 16 + l15] =
                    f32_to_bf16_bits(acc[t][j] + bv[t]);
        }
}

// ---------------- W -> fragment-ordered bf16 WTf ----------------
__device__ inline void wt_frag(const float* __restrict__ W, short* __restrict__ out,
                               int K, int N, int u)
{
    const int lane = u & 63;
    const int rest = u >> 6;
    const int KS   = K >> 5;
    const int ks   = rest % KS;
    const int tg   = rest / KS;
    const int n    = tg * 16 + (lane & 15);
    const int kb   = ks * 32 + (lane >> 4) * 8;
    short8 s;
#pragma unroll
    for (int e = 0; e < 8; ++e) s[e] = f32_to_bf16_bits(W[(size_t)(kb + e) * N + n]);
    *reinterpret_cast<short8*>(&out[(size_t)u * 8]) = s;
}

// ================= prep: bin_hist (blocks 0..BIN_BLOCKS-1) + wt transposes =================
__global__ __launch_bounds__(256) void prep_kernel(const int* __restrict__ dst,
                                                   int* __restrict__ hist_g, int E,
                                                   const float* __restrict__ W1, short* __restrict__ WT1,
                                                   const float* __restrict__ W2, short* __restrict__ WT2,
                                                   const float* __restrict__ W3, short* __restrict__ WT3)
{
    if (blockIdx.x < BIN_BLOCKS) {
        __shared__ int hist[NBUCK];
        for (int t = threadIdx.x; t < NBUCK; t += 256) hist[t] = 0;
        __syncthreads();
        const int chunk = (E + BIN_BLOCKS - 1) / BIN_BLOCKS;
        const int beg = blockIdx.x * chunk;
        const int end = min(beg + chunk, E);
        for (int i = beg + threadIdx.x; i < end; i += 256)
            atomicAdd(&hist[dst[i] >> BSHIFT], 1);
        __syncthreads();
        for (int t = threadIdx.x; t < NBUCK; t += 256)
            hist_g[blockIdx.x * NBUCK + t] = hist[t];
    } else {
        const int u = (blockIdx.x - BIN_BLOCKS) * 256 + threadIdx.x;
        if (u < 4096)             wt_frag(W1, WT1, 256, 128, u);
        else if (u < 4096 + 2048) wt_frag(W2, WT2, 128, 128, u - 4096);
        else if (u < 7168)        wt_frag(W3, WT3, 128, 64,  u - 6144);
    }
}

__global__ __launch_bounds__(BIN_BLOCKS) void bin_scan_blocks(const int* __restrict__ hist_g,
                                                              int* __restrict__ blockbase,
                                                              int* __restrict__ tot)
{
    __shared__ int s[BIN_BLOCKS];
    const int b = blockIdx.x;
    const int t = threadIdx.x;
    const int v = hist_g[t * NBUCK + b];
    s[t] = v;
    __syncthreads();
#pragma unroll
    for (int off = 1; off < BIN_BLOCKS; off <<= 1) {
        const int tmp = (t >= off) ? s[t - off] : 0;
        __syncthreads();
        s[t] += tmp;
        __syncthreads();
    }
    blockbase[t * NBUCK + b] = s[t] - v;
    if (t == BIN_BLOCKS - 1) tot[b] = s[t];
}

__global__ __launch_bounds__(256) void bin_scan_tot(const int* __restrict__ tot,
                                                    int* __restrict__ bucket_base)
{
    __shared__ int psum[256];
    const int t = threadIdx.x;
    int vals[4];
    int s = 0;
#pragma unroll
    for (int j = 0; j < 4; ++j) {
        const int idx = t * 4 + j;
        vals[j] = (idx < NBUCK) ? tot[idx] : 0;
        s += vals[j];
    }
    psum[t] = s;
    __syncthreads();
#pragma unroll
    for (int off = 1; off < 256; off <<= 1) {
        const int tmp = (t >= off) ? psum[t - off] : 0;
        __syncthreads();
        psum[t] += tmp;
        __syncthreads();
    }
    int run = psum[t] - s;
#pragma unroll
    for (int j = 0; j < 4; ++j) {
        const int idx = t * 4 + j;
        if (idx < NBUCK) bucket_base[idx] = run;
        run += vals[j];
    }
    if (t == 255) bucket_base[NBUCK] = run;
}

__global__ __launch_bounds__(256) void bin_write(const int* __restrict__ src,
                                                 const int* __restrict__ dst,
                                                 const float* __restrict__ w,
                                                 const int* __restrict__ blockbase,
                                                 const int* __restrict__ bucket_base,
                                                 int2* __restrict__ tmp, int E)
{
    __shared__ int cur[NBUCK];
    for (int t = threadIdx.x; t < NBUCK; t += 256)
        cur[t] = bucket_base[t] + blockbase[blockIdx.x * NBUCK + t];
    __syncthreads();
    const int chunk = (E + BIN_BLOCKS - 1) / BIN_BLOCKS;
    const int beg = blockIdx.x * chunk;
    const int end = min(beg + chunk, E);
    for (int i = beg + threadIdx.x; i < end; i += 256) {
        const int d = dst[i];
        const int pos = atomicAdd(&cur[d >> BSHIFT], 1);
        tmp[pos] = make_int2((src[i] << BSHIFT) | (d & (BSIZE - 1)), __float_as_int(w[i]));
    }
}

// Pass D: one block per bucket. row_ptr + node-sorted packed 4B csr: (src<<16)|bf16(w)
__global__ __launch_bounds__(256) void fine_fill2(const int2* __restrict__ tmp,
                                                  const int* __restrict__ bucket_base,
                                                  unsigned int* __restrict__ csr_ew,
                                                  int* __restrict__ row_ptr)
{
    __shared__ int hist[BSIZE];
    __shared__ int basel[BSIZE];
    const int b    = blockIdx.x;
    const int t    = threadIdx.x;
    const int rbeg = bucket_base[b];
    const int rend = bucket_base[b + 1];

    if (t < BSIZE) hist[t] = 0;
    __syncthreads();
    for (int i = rbeg + t; i < rend; i += 256)
        atomicAdd(&hist[((unsigned)tmp[i].x) & (BSIZE - 1)], 1);
    __syncthreads();

    if (t < BSIZE) {
        const int v = hist[t];
        int inc = v;
#pragma unroll
        for (int off = 1; off < BSIZE; off <<= 1) {
            const int u = __shfl_up(inc, off, 64);
            if (t >= off) inc += u;
        }
        const int excl = rbeg + inc - v;
        basel[t] = excl;
        const int node = (b << BSHIFT) + t;
        if (node < N_NODES) row_ptr[node] = excl;
        if (b == NBUCK - 1 && t == 0) row_ptr[N_NODES] = bucket_base[NBUCK];
    }
    __syncthreads();

    for (int i = rbeg + t; i < rend; i += 256) {
        const int2 e = tmp[i];
        const unsigned ex = (unsigned)e.x;
        const int pos = atomicAdd(&basel[ex & (BSIZE - 1)], 1);
        const unsigned wb = (unsigned short)f32_to_bf16_bits(__int_as_float(e.y));
        csr_ew[pos] = ((ex >> BSHIFT) << 16) | wb;
    }
}

// ---------------- pull (bf16 h, D=64): 4 nodes/wave, 8-deep gathers, f32 out ----------------
__global__ __launch_bounds__(256) void pull64_bf(const unsigned int* __restrict__ h,
                                                 const int* __restrict__ row_ptr,
                                                 const unsigned int* __restrict__ csr_ew,
                                                 float4* __restrict__ out, int n_nodes)
{
    const int wave = threadIdx.x >> 6;
    const int lane = threadIdx.x & 63;
    const int q    = lane >> 4;
    const int l16  = lane & 15;
    const int node = blockIdx.x * 16 + wave * 4 + q;

    int beg = 0, end = 0;
    if (node < n_nodes) { beg = row_ptr[node]; end = row_ptr[node + 1]; }

    float ax[4][2], ay[4][2];
#pragma unroll
    for (int u = 0; u < 4; ++u)
#pragma unroll
        for (int jj = 0; jj < 2; ++jj) { ax[u][jj] = 0.f; ay[u][jj] = 0.f; }

    unsigned ew = (beg + l16 < end) ? csr_ew[beg + l16] : 0u;
    for (int c = beg; c < end; c += 16) {
        const int nidx = c + 16 + l16;
        const unsigned ew_next = (nidx < end) ? csr_ew[nidx] : 0u;
        const int cnt = min(16, end - c);

        for (int j = 0; j < cnt; j += 8) {
            unsigned e[8];
#pragma unroll
            for (int u = 0; u < 8; ++u) {
                const unsigned v = __shfl(ew, j + u, 16);
                e[u] = (j + u < cnt) ? v : 0u;
            }
            uint2 p[8];
#pragma unroll
            for (int u = 0; u < 8; ++u)
                p[u] = *reinterpret_cast<const uint2*>(&h[(size_t)(e[u] >> 16) * 32 + l16 * 2]);
#pragma unroll
            for (int u = 0; u < 8; ++u) {
                const float wv = __int_as_float(e[u] << 16);
                ax[u & 3][0] = fmaf(__int_as_float(p[u].x << 16), wv, ax[u & 3][0]);
                ay[u & 3][0] = fmaf(__int_as_float(p[u].x & 0xffff0000u), wv, ay[u & 3][0]);
                ax[u & 3][1] = fmaf(__int_as_float(p[u].y << 16), wv, ax[u & 3][1]);
                ay[u & 3][1] = fmaf(__int_as_float(p[u].y & 0xffff0000u), wv, ay[u & 3][1]);
            }
        }
        ew = ew_next;
    }

    if (node < n_nodes) {
        float4 o;
        o.x = (ax[0][0] + ax[1][0]) + (ax[2][0] + ax[3][0]);
        o.y = (ay[0][0] + ay[1][0]) + (ay[2][0] + ay[3][0]);
        o.z = (ax[0][1] + ax[1][1]) + (ax[2][1] + ax[3][1]);
        o.w = (ay[0][1] + ay[1][1]) + (ay[2][1] + ay[3][1]);
        out[(size_t)node * 16 + l16] = o;
    }
}

extern "C" void kernel_launch(void* const* d_in, const int* in_sizes, int n_in,
                              void* d_out, int out_size, void* d_ws, size_t ws_size,
                              hipStream_t stream)
{
    const float* x   = (const float*)d_in[0];
    const int*   src = (const int*)  d_in[1];
    const int*   dst = (const int*)  d_in[2];
    const float* w   = (const float*)d_in[3];
    const float* W1  = (const float*)d_in[4];
    const float* b1  = (const float*)d_in[5];
    const float* W2  = (const float*)d_in[6];
    const float* b2  = (const float*)d_in[7];
    const float* W3  = (const float*)d_in[8];
    const float* b3  = (const float*)d_in[9];

    const int E = in_sizes[1];
    const int M = N_NODES;

    // workspace layout
    short* hA  = (short*)d_ws;                        // M*128 bf16 (h1 / h3)
    short* hB  = hA + (size_t)M * 128;                // M*128 bf16 (h2)
    short* WT1 = hB + (size_t)M * 128;                // frag-ordered
    short* WT2 = WT1 + 128 * 256;
    short* WT3 = WT2 + 128 * 128;
    unsigned int* csr_ew = (unsigned int*)(WT3 + 64 * 128);  // E u32
    int2*  tmp_ew      = (int2*)(csr_ew + ((E + 1) & ~1));   // E pairs
    int*   row_ptr     = (int*)(tmp_ew + E);          // 50048
    int*   hist_g      = row_ptr + 50048;             // 512*782 -> pad 401408
    int*   blockbase   = hist_g + 401408;             // 512*782 -> pad 401408
    int*   bucket_base = blockbase + 401408;          // 783 -> pad 1024
    int*   tot         = bucket_base + 1024;          // 782 -> pad 1024

    // ---- build (weights + CSR), no global atomics ----
    prep_kernel<<<BIN_BLOCKS + 28, 256, 0, stream>>>(dst, hist_g, E, W1, WT1, W2, WT2, W3, WT3);
    bin_scan_blocks<<<NBUCK, BIN_BLOCKS, 0, stream>>>(hist_g, blockbase, tot);
    bin_scan_tot<<<1, 256, 0, stream>>>(tot, bucket_base);
    bin_write<<<BIN_BLOCKS, 256, 0, stream>>>(src, dst, w, blockbase, bucket_base, tmp_ew, E);
    fine_fill2<<<NBUCK, 256, 0, stream>>>(tmp_ew, bucket_base, csr_ew, row_ptr);

    // ---- Layer 1 GEMM: x @ W1 -> h1 (hA) ----
    mfma_gemm<256, 128, true><<<(M + 63) / 64, 256, 0, stream>>>(x, WT1, b1, hA, M);

    const int fb = (M + 31) / 32;   // 1563 fused blocks
    // ---- Fused: pull(h1) -> relu -> @W2 -> h2 (hB) ----
    fused_pull_gemm<128, 128><<<fb, 256, 0, stream>>>((const unsigned int*)hA, row_ptr, csr_ew,
                                                      WT2, b2, hB, M);
    // ---- Fused: pull(h2) -> relu -> @W3 -> h3 (hA) ----
    fused_pull_gemm<128, 64><<<fb, 256, 0, stream>>>((const unsigned int*)hB, row_ptr, csr_ew,
                                                     WT3, b3, hA, M);
    // ---- Final pull: out = segsum(h3) ----
    pull64_bf<<<(M + 15) / 16, 256, 0, stream>>>((const unsigned int*)hA, row_ptr, csr_ew,
                                                 (float4*)d_out, M);
}

// Round 17
// 135.168 us; speedup vs baseline: 1.0552x; 1.0038x over previous
//
#include <hip/hip_runtime.h>
#include <hip/hip_bf16.h>

#define N_NODES 50000
#define BSHIFT  6
#define BSIZE   64
#define NBUCK   ((N_NODES + BSIZE - 1) / BSIZE)   // 782
#define BIN_BLOCKS 512

using short8  = __attribute__((ext_vector_type(8))) short;
using short4v = __attribute__((ext_vector_type(4))) short;
using floatx4 = __attribute__((ext_vector_type(4))) float;

__device__ inline short f32_to_bf16_bits(float f) {
    __hip_bfloat16 h = __float2bfloat16(f);
    return *reinterpret_cast<short*>(&h);
}

// ================= MERGED: per-bucket block-scan (blocks 0..NBUCK-1)
//                   + layer-1 GEMM  (blocks NBUCK..NBUCK+781), 512 threads =================
// GEMM: C_bf16[M,128] = bf16(x[M,256]) @ W1 + b1. 8 waves = 4 row-groups x 2 col-groups,
// wave = 16 rows x 64 cols (4 col-tiles).
__global__ __launch_bounds__(512) void scan_gemm1(const int* __restrict__ hist_g,
                                                  int* __restrict__ blockbase,
                                                  int* __restrict__ tot,
                                                  const float* __restrict__ x,
                                                  const short* __restrict__ WTf,
                                                  const float* __restrict__ bias,
                                                  short* __restrict__ C, int M)
{
    if (blockIdx.x < NBUCK) {
        __shared__ int s[BIN_BLOCKS];
        const int b = blockIdx.x;
        const int t = threadIdx.x;
        const int v = hist_g[t * NBUCK + b];
        s[t] = v;
        __syncthreads();
#pragma unroll
        for (int off = 1; off < BIN_BLOCKS; off <<= 1) {
            const int tmp = (t >= off) ? s[t - off] : 0;
            __syncthreads();
            s[t] += tmp;
            __syncthreads();
        }
        blockbase[t * NBUCK + b] = s[t] - v;
        if (t == BIN_BLOCKS - 1) tot[b] = s[t];
        return;
    }

    // ---------------- layer-1 GEMM ----------------
    constexpr int K  = 256;
    constexpr int KS = K / 32;        // 8
    constexpr int LK = K + 8;

    __shared__ __align__(16) short As[64][LK];

    const int bid  = blockIdx.x - NBUCK;
    const int r0   = bid * 64;
    const int tid  = threadIdx.x;
    const int wave = tid >> 6;        // 0..7
    const int lane = tid & 63;
    const int l15  = lane & 15;
    const int lk   = (lane >> 4) * 8;
    const int wr   = wave >> 1;       // 0..3 row-groups (16 rows each)
    const int wc   = wave & 1;        // 0..1 col-groups (64 cols each)

    // stage A (64 rows x 256) as bf16, coalesced: 4096 float4 / 512 thr = 8 iters
#pragma unroll
    for (int it = 0; it < 8; ++it) {
        const int idx = it * 512 + tid;
        const int row = idx >> 6;
        const int c4  = idx & 63;
        const int gr  = min(r0 + row, M - 1);
        const float4 v = *reinterpret_cast<const float4*>(&x[(size_t)gr * K + c4 * 4]);
        short4v sv;
        sv[0] = f32_to_bf16_bits(v.x); sv[1] = f32_to_bf16_bits(v.y);
        sv[2] = f32_to_bf16_bits(v.z); sv[3] = f32_to_bf16_bits(v.w);
        *reinterpret_cast<short4v*>(&As[row][c4 * 4]) = sv;
    }
    __syncthreads();

    float bv[4];
#pragma unroll
    for (int t = 0; t < 4; ++t) bv[t] = bias[wc * 64 + t * 16 + l15];

    floatx4 acc[4];
#pragma unroll
    for (int t = 0; t < 4; ++t) acc[t] = (floatx4){0.f, 0.f, 0.f, 0.f};

#pragma unroll
    for (int ks = 0; ks < KS; ++ks) {
        short8 b[4];
#pragma unroll
        for (int t = 0; t < 4; ++t) {
            const int tg = wc * 4 + t;       // global col-tile 0..7
            b[t] = *reinterpret_cast<const short8*>(&WTf[((size_t)(tg * KS + ks) * 64 + lane) * 8]);
        }
        const short8 a = *reinterpret_cast<const short8*>(&As[wr * 16 + l15][ks * 32 + lk]);
#pragma unroll
        for (int t = 0; t < 4; ++t)
            acc[t] = __builtin_amdgcn_mfma_f32_16x16x32_bf16(a, b[t], acc[t], 0, 0, 0);
    }

    const int rowg = (lane >> 4) * 4;
#pragma unroll
    for (int t = 0; t < 4; ++t)
#pragma unroll
        for (int j = 0; j < 4; ++j) {
            const int gr = r0 + wr * 16 + rowg + j;
            if (gr < M)
                C[(size_t)gr * 128 + wc * 64 + t * 16 + l15] =
                    f32_to_bf16_bits(acc[t][j] + bv[t]);
        }
}

// ---------------- FUSED: pull (32 nodes, D=128) -> relu -> GEMM ----------------
template<int K, int N>
__global__ __launch_bounds__(256) void fused_pull_gemm(const unsigned int* __restrict__ h,
                                                       const int* __restrict__ row_ptr,
                                                       const unsigned int* __restrict__ csr_ew,
                                                       const short* __restrict__ WTf,
                                                       const float* __restrict__ bias,
                                                       short* __restrict__ C, int M)
{
    static_assert(K == 128, "pull input dim is 128");
    constexpr int KS   = K / 32;
    constexpr int LK   = K + 8;
    constexpr int COLT = N / 32;            // col-tiles per wave (4 or 2)

    __shared__ __align__(16) short As[32][LK];

    const int tid  = threadIdx.x;
    const int wave = tid >> 6;
    const int lane = tid & 63;
    const int q    = lane >> 4;
    const int l16  = lane & 15;
    const int r0   = blockIdx.x * 32;

#pragma unroll
    for (int rnd = 0; rnd < 2; ++rnd) {
        const int lrow = wave * 8 + rnd * 4 + q;
        const int node = r0 + lrow;
        int beg = 0, end = 0;
        if (node < M) { beg = row_ptr[node]; end = row_ptr[node + 1]; }

        float ax[4][4], ay[4][4];
#pragma unroll
        for (int u = 0; u < 4; ++u)
#pragma unroll
            for (int jj = 0; jj < 4; ++jj) { ax[u][jj] = 0.f; ay[u][jj] = 0.f; }

        unsigned ew = (beg + l16 < end) ? csr_ew[beg + l16] : 0u;
        for (int c = beg; c < end; c += 16) {
            const int nidx = c + 16 + l16;
            const unsigned ew_next = (nidx < end) ? csr_ew[nidx] : 0u;
            const int cnt = min(16, end - c);

            for (int j = 0; j < cnt; j += 8) {
                unsigned e[8];
#pragma unroll
                for (int u = 0; u < 8; ++u) {
                    const unsigned v = __shfl(ew, j + u, 16);
                    e[u] = (j + u < cnt) ? v : 0u;       // pad: src=0, w=+0.0
                }
                uint4 p[8];
#pragma unroll
                for (int u = 0; u < 8; ++u)
                    p[u] = *reinterpret_cast<const uint4*>(&h[(size_t)(e[u] >> 16) * 64 + l16 * 4]);
#pragma unroll
                for (int u = 0; u < 8; ++u) {
                    const float wv = __int_as_float(e[u] << 16);
                    const unsigned* pp = reinterpret_cast<const unsigned*>(&p[u]);
#pragma unroll
                    for (int jj = 0; jj < 4; ++jj) {
                        ax[u & 3][jj] = fmaf(__int_as_float(pp[jj] << 16), wv, ax[u & 3][jj]);
                        ay[u & 3][jj] = fmaf(__int_as_float(pp[jj] & 0xffff0000u), wv, ay[u & 3][jj]);
                    }
                }
            }
            ew = ew_next;
        }

        uint4 o;
        unsigned* ov = reinterpret_cast<unsigned*>(&o);
#pragma unroll
        for (int jj = 0; jj < 4; ++jj) {
            float axs = (ax[0][jj] + ax[1][jj]) + (ax[2][jj] + ax[3][jj]);
            float ays = (ay[0][jj] + ay[1][jj]) + (ay[2][jj] + ay[3][jj]);
            axs = fmaxf(axs, 0.f); ays = fmaxf(ays, 0.f);      // relu
            ov[jj] = (unsigned)(unsigned short)f32_to_bf16_bits(axs) |
                     ((unsigned)(unsigned short)f32_to_bf16_bits(ays) << 16);
        }
        *reinterpret_cast<uint4*>(&As[lrow][l16 * 8]) = o;
    }
    __syncthreads();

    // ---- GEMM from LDS (4 waves = 2 row-groups x 2 col-groups) ----
    const int l15 = lane & 15;
    const int lk  = (lane >> 4) * 8;
    const int wr  = wave >> 1;
    const int wc  = wave & 1;

    float bv[COLT];
#pragma unroll
    for (int t = 0; t < COLT; ++t) bv[t] = bias[wc * (N / 2) + t * 16 + l15];

    floatx4 acc[COLT];
#pragma unroll
    for (int t = 0; t < COLT; ++t) acc[t] = (floatx4){0.f, 0.f, 0.f, 0.f};

#pragma unroll
    for (int ks = 0; ks < KS; ++ks) {
        short8 b[COLT];
#pragma unroll
        for (int t = 0; t < COLT; ++t) {
            const int tg = wc * COLT + t;
            b[t] = *reinterpret_cast<const short8*>(&WTf[((size_t)(tg * KS + ks) * 64 + lane) * 8]);
        }
        const short8 a = *reinterpret_cast<const short8*>(&As[wr * 16 + l15][ks * 32 + lk]);
#pragma unroll
        for (int t = 0; t < COLT; ++t)
            acc[t] = __builtin_amdgcn_mfma_f32_16x16x32_bf16(a, b[t], acc[t], 0, 0, 0);
    }

    const int rowg = (lane >> 4) * 4;
#pragma unroll
    for (int t = 0; t < COLT; ++t)
#pragma unroll
        for (int j = 0; j < 4; ++j) {
            const int gr = r0 + wr * 16 + rowg + j;
            if (gr < M)
                C[(size_t)gr * N + wc * (N / 2) + t * 16 + l15] =
                    f32_to_bf16_bits(acc[t][j] + bv[t]);
        }
}

// ---------------- W -> fragment-ordered bf16 WTf ----------------
__device__ inline void wt_frag(const float* __restrict__ W, short* __restrict__ out,
                               int K, int N, int u)
{
    const int lane = u & 63;
    const int rest = u >> 6;
    const int KS   = K >> 5;
    const int ks   = rest % KS;
    const int tg   = rest / KS;
    const int n    = tg * 16 + (lane & 15);
    const int kb   = ks * 32 + (lane >> 4) * 8;
    short8 s;
#pragma unroll
    for (int e = 0; e < 8; ++e) s[e] = f32_to_bf16_bits(W[(size_t)(kb + e) * N + n]);
    *reinterpret_cast<short8*>(&out[(size_t)u * 8]) = s;
}

// ================= prep: bin_hist (blocks 0..BIN_BLOCKS-1) + wt transposes =================
__global__ __launch_bounds__(256) void prep_kernel(const int* __restrict__ dst,
                                                   int* __restrict__ hist_g, int E,
                                                   const float* __restrict__ W1, short* __restrict__ WT1,
                                                   const float* __restrict__ W2, short* __restrict__ WT2,
                                                   const float* __restrict__ W3, short* __restrict__ WT3)
{
    if (blockIdx.x < BIN_BLOCKS) {
        __shared__ int hist[NBUCK];
        for (int t = threadIdx.x; t < NBUCK; t += 256) hist[t] = 0;
        __syncthreads();
        const int chunk = (E + BIN_BLOCKS - 1) / BIN_BLOCKS;
        const int beg = blockIdx.x * chunk;
        const int end = min(beg + chunk, E);
        for (int i = beg + threadIdx.x; i < end; i += 256)
            atomicAdd(&hist[dst[i] >> BSHIFT], 1);
        __syncthreads();
        for (int t = threadIdx.x; t < NBUCK; t += 256)
            hist_g[blockIdx.x * NBUCK + t] = hist[t];
    } else {
        const int u = (blockIdx.x - BIN_BLOCKS) * 256 + threadIdx.x;
        if (u < 4096)             wt_frag(W1, WT1, 256, 128, u);
        else if (u < 4096 + 2048) wt_frag(W2, WT2, 128, 128, u - 4096);
        else if (u < 7168)        wt_frag(W3, WT3, 128, 64,  u - 6144);
    }
}

// ---------------- bin_write: inline bucket_base scan + localized scatter ----------------
__global__ __launch_bounds__(256) void bin_write(const int* __restrict__ src,
                                                 const int* __restrict__ dst,
                                                 const float* __restrict__ w,
                                                 const int* __restrict__ blockbase,
                                                 const int* __restrict__ tot,
                                                 int* __restrict__ bucket_base_out,
                                                 int2* __restrict__ tmp, int E)
{
    __shared__ int cur[NBUCK];
    __shared__ int psum[256];
    const int t = threadIdx.x;

    // inline exclusive scan of tot[0..NBUCK) (every block computes it; block 0 publishes)
    int vals[4];
    int sacc = 0;
#pragma unroll
    for (int j = 0; j < 4; ++j) {
        const int idx = t * 4 + j;
        vals[j] = (idx < NBUCK) ? tot[idx] : 0;
        sacc += vals[j];
    }
    psum[t] = sacc;
    __syncthreads();
#pragma unroll
    for (int off = 1; off < 256; off <<= 1) {
        const int tmpv = (t >= off) ? psum[t - off] : 0;
        __syncthreads();
        psum[t] += tmpv;
        __syncthreads();
    }
    int run = psum[t] - sacc;
#pragma unroll
    for (int j = 0; j < 4; ++j) {
        const int idx = t * 4 + j;
        if (idx < NBUCK) {
            cur[idx] = run + blockbase[blockIdx.x * NBUCK + idx];
            if (blockIdx.x == 0) bucket_base_out[idx] = run;
        }
        run += vals[j];
    }
    if (blockIdx.x == 0 && t == 255) bucket_base_out[NBUCK] = run;   // == E
    __syncthreads();

    const int chunk = (E + BIN_BLOCKS - 1) / BIN_BLOCKS;
    const int beg = blockIdx.x * chunk;
    const int end = min(beg + chunk, E);
    for (int i = beg + t; i < end; i += 256) {
        const int d = dst[i];
        const int pos = atomicAdd(&cur[d >> BSHIFT], 1);
        tmp[pos] = make_int2((src[i] << BSHIFT) | (d & (BSIZE - 1)), __float_as_int(w[i]));
    }
}

// Pass D: one block per bucket. row_ptr + node-sorted packed 4B csr: (src<<16)|bf16(w)
__global__ __launch_bounds__(256) void fine_fill2(const int2* __restrict__ tmp,
                                                  const int* __restrict__ bucket_base,
                                                  unsigned int* __restrict__ csr_ew,
                                                  int* __restrict__ row_ptr)
{
    __shared__ int hist[BSIZE];
    __shared__ int basel[BSIZE];
    const int b    = blockIdx.x;
    const int t    = threadIdx.x;
    const int rbeg = bucket_base[b];
    const int rend = bucket_base[b + 1];

    if (t < BSIZE) hist[t] = 0;
    __syncthreads();
    for (int i = rbeg + t; i < rend; i += 256)
        atomicAdd(&hist[((unsigned)tmp[i].x) & (BSIZE - 1)], 1);
    __syncthreads();

    if (t < BSIZE) {
        const int v = hist[t];
        int inc = v;
#pragma unroll
        for (int off = 1; off < BSIZE; off <<= 1) {
            const int u = __shfl_up(inc, off, 64);
            if (t >= off) inc += u;
        }
        const int excl = rbeg + inc - v;
        basel[t] = excl;
        const int node = (b << BSHIFT) + t;
        if (node < N_NODES) row_ptr[node] = excl;
        if (b == NBUCK - 1 && t == 0) row_ptr[N_NODES] = bucket_base[NBUCK];
    }
    __syncthreads();

    for (int i = rbeg + t; i < rend; i += 256) {
        const int2 e = tmp[i];
        const unsigned ex = (unsigned)e.x;
        const int pos = atomicAdd(&basel[ex & (BSIZE - 1)], 1);
        const unsigned wb = (unsigned short)f32_to_bf16_bits(__int_as_float(e.y));
        csr_ew[pos] = ((ex >> BSHIFT) << 16) | wb;
    }
}

// ---------------- pull (bf16 h, D=64): 4 nodes/wave, 8-deep gathers, f32 out ----------------
__global__ __launch_bounds__(256) void pull64_bf(const unsigned int* __restrict__ h,
                                                 const int* __restrict__ row_ptr,
                                                 const unsigned int* __restrict__ csr_ew,
                                                 float4* __restrict__ out, int n_nodes)
{
    const int wave = threadIdx.x >> 6;
    const int lane = threadIdx.x & 63;
    const int q    = lane >> 4;
    const int l16  = lane & 15;
    const int node = blockIdx.x * 16 + wave * 4 + q;

    int beg = 0, end = 0;
    if (node < n_nodes) { beg = row_ptr[node]; end = row_ptr[node + 1]; }

    float ax[4][2], ay[4][2];
#pragma unroll
    for (int u = 0; u < 4; ++u)
#pragma unroll
        for (int jj = 0; jj < 2; ++jj) { ax[u][jj] = 0.f; ay[u][jj] = 0.f; }

    unsigned ew = (beg + l16 < end) ? csr_ew[beg + l16] : 0u;
    for (int c = beg; c < end; c += 16) {
        const int nidx = c + 16 + l16;
        const unsigned ew_next = (nidx < end) ? csr_ew[nidx] : 0u;
        const int cnt = min(16, end - c);

        for (int j = 0; j < cnt; j += 8) {
            unsigned e[8];
#pragma unroll
            for (int u = 0; u < 8; ++u) {
                const unsigned v = __shfl(ew, j + u, 16);
                e[u] = (j + u < cnt) ? v : 0u;
            }
            uint2 p[8];
#pragma unroll
            for (int u = 0; u < 8; ++u)
                p[u] = *reinterpret_cast<const uint2*>(&h[(size_t)(e[u] >> 16) * 32 + l16 * 2]);
#pragma unroll
            for (int u = 0; u < 8; ++u) {
                const float wv = __int_as_float(e[u] << 16);
                ax[u & 3][0] = fmaf(__int_as_float(p[u].x << 16), wv, ax[u & 3][0]);
                ay[u & 3][0] = fmaf(__int_as_float(p[u].x & 0xffff0000u), wv, ay[u & 3][0]);
                ax[u & 3][1] = fmaf(__int_as_float(p[u].y << 16), wv, ax[u & 3][1]);
                ay[u & 3][1] = fmaf(__int_as_float(p[u].y & 0xffff0000u), wv, ay[u & 3][1]);
            }
        }
        ew = ew_next;
    }

    if (node < n_nodes) {
        float4 o;
        o.x = (ax[0][0] + ax[1][0]) + (ax[2][0] + ax[3][0]);
        o.y = (ay[0][0] + ay[1][0]) + (ay[2][0] + ay[3][0]);
        o.z = (ax[0][1] + ax[1][1]) + (ax[2][1] + ax[3][1]);
        o.w = (ay[0][1] + ay[1][1]) + (ay[2][1] + ay[3][1]);
        out[(size_t)node * 16 + l16] = o;
    }
}

extern "C" void kernel_launch(void* const* d_in, const int* in_sizes, int n_in,
                              void* d_out, int out_size, void* d_ws, size_t ws_size,
                              hipStream_t stream)
{
    const float* x   = (const float*)d_in[0];
    const int*   src = (const int*)  d_in[1];
    const int*   dst = (const int*)  d_in[2];
    const float* w   = (const float*)d_in[3];
    const float* W1  = (const float*)d_in[4];
    const float* b1  = (const float*)d_in[5];
    const float* W2  = (const float*)d_in[6];
    const float* b2  = (const float*)d_in[7];
    const float* W3  = (const float*)d_in[8];
    const float* b3  = (const float*)d_in[9];

    const int E = in_sizes[1];
    const int M = N_NODES;

    // workspace layout
    short* hA  = (short*)d_ws;                        // M*128 bf16 (h1 / h3)
    short* hB  = hA + (size_t)M * 128;                // M*128 bf16 (h2)
    short* WT1 = hB + (size_t)M * 128;                // frag-ordered
    short* WT2 = WT1 + 128 * 256;
    short* WT3 = WT2 + 128 * 128;
    unsigned int* csr_ew = (unsigned int*)(WT3 + 64 * 128);  // E u32
    int2*  tmp_ew      = (int2*)(csr_ew + ((E + 1) & ~1));   // E pairs
    int*   row_ptr     = (int*)(tmp_ew + E);          // 50048
    int*   hist_g      = row_ptr + 50048;             // 512*782 -> pad 401408
    int*   blockbase   = hist_g + 401408;             // 512*782 -> pad 401408
    int*   bucket_base = blockbase + 401408;          // 783 -> pad 1024
    int*   tot         = bucket_base + 1024;          // 782 -> pad 1024

    // ---- [1] prep: histogram + weight transposes (independent work in one grid) ----
    prep_kernel<<<BIN_BLOCKS + 28, 256, 0, stream>>>(dst, hist_g, E, W1, WT1, W2, WT2, W3, WT3);

    // ---- [2] per-bucket scan  ||  layer-1 GEMM (independent -> one grid, overlap) ----
    scan_gemm1<<<NBUCK + (M + 63) / 64, 512, 0, stream>>>(hist_g, blockbase, tot,
                                                          x, WT1, b1, hA, M);

    // ---- [3] binned scatter (inline bucket_base scan; block 0 publishes it) ----
    bin_write<<<BIN_BLOCKS, 256, 0, stream>>>(src, dst, w, blockbase, tot, bucket_base, tmp_ew, E);

    // ---- [4] per-bucket node sort -> csr_ew + row_ptr ----
    fine_fill2<<<NBUCK, 256, 0, stream>>>(tmp_ew, bucket_base, csr_ew, row_ptr);

    const int fb = (M + 31) / 32;   // 1563 fused blocks
    // ---- [5] Fused: pull(h1) -> relu -> @W2 -> h2 (hB) ----
    fused_pull_gemm<128, 128><<<fb, 256, 0, stream>>>((const unsigned int*)hA, row_ptr, csr_ew,
                                                      WT2, b2, hB, M);
    // ---- [6] Fused: pull(h2) -> relu -> @W3 -> h3 (hA) ----
    fused_pull_gemm<128, 64><<<fb, 256, 0, stream>>>((const unsigned int*)hB, row_ptr, csr_ew,
                                                     WT3, b3, hA, M);
    // ---- [7] Final pull: out = segsum(h3) ----
    pull64_bf<<<(M + 15) / 16, 256, 0, stream>>>((const unsigned int*)hA, row_ptr, csr_ew,
                                                 (float4*)d_out, M);
}